// Round 2
// baseline (11.151 us; speedup 1.0000x reference)
//
#include <hip/hip_runtime.h>
#include <hip/hip_bf16.h>

// Soft-codebook quantization, t-Student kernel, STE forward.
// Forward output is numerically exactly `hard` = nearest codebook value
// (codebook = integers -7..8), ties toward the LOWER value (argmax first-index).
// hard = clamp(ceil(x - 0.5), -7, 8). Pure memory-bound elementwise op.
//
// Perf structure: 2x float4 per thread (32 B/lane) -> ILP=2 outstanding VMEM
// per wave; 2048 blocks x 256 threads covers 4 MiElem exactly.

__device__ __forceinline__ float quant1(float v) {
    // ceil(v - 0.5) == round-to-nearest with ties DOWN (exact in fp32 for |v|<2^23)
    float r = ceilf(v - 0.5f);
    r = fmaxf(-7.0f, fminf(8.0f, r));
    return r + 0.0f;  // normalize -0.0 -> +0.0
}

__device__ __forceinline__ float4 quant4(float4 v) {
    float4 r;
    r.x = quant1(v.x);
    r.y = quant1(v.y);
    r.z = quant1(v.z);
    r.w = quant1(v.w);
    return r;
}

__global__ void __launch_bounds__(256) quant_kernel(const float4* __restrict__ x,
                                                    float4* __restrict__ out,
                                                    int n4) {
    // Each block covers 512 consecutive float4s: thread t handles base+t and base+t+256.
    int base = blockIdx.x * 512 + threadIdx.x;
    int i0 = base;
    int i1 = base + 256;
    if (i1 < n4) {
        // fast path: both in range; issue both loads before any use
        float4 v0 = x[i0];
        float4 v1 = x[i1];
        out[i0] = quant4(v0);
        out[i1] = quant4(v1);
    } else {
        if (i0 < n4) out[i0] = quant4(x[i0]);
    }
}

extern "C" void kernel_launch(void* const* d_in, const int* in_sizes, int n_in,
                              void* d_out, int out_size, void* d_ws, size_t ws_size,
                              hipStream_t stream) {
    const float* x = (const float*)d_in[0];
    float* out = (float*)d_out;
    int n = out_size;            // 16*64*64*64 = 4194304, divisible by 4
    int n4 = n / 4;              // 1048576 float4 elements
    int block = 256;
    int grid = (n4 + 511) / 512; // 2048 blocks, 2 float4 per thread
    quant_kernel<<<grid, block, 0, stream>>>((const float4*)x, (float4*)out, n4);
}

// Round 4
// 11.094 us; speedup vs baseline: 1.0051x; 1.0051x over previous
//
#include <hip/hip_runtime.h>
#include <hip/hip_bf16.h>

// Soft-codebook quantization, t-Student kernel, STE forward.
// Forward output is numerically exactly `hard` = nearest codebook value
// (codebook = integers -7..8), ties toward the LOWER value (argmax first-index).
// hard = clamp(ceil(x - 0.5), -7, 8). Pure memory-bound elementwise op.
//
// Perf structure: 4x 16B-vector per thread (64 B/lane), all loads issued
// before stores (MLP=4). 1024 blocks x 256 threads covers 4 MiElem exactly.
// Non-temporal hints (zero reuse). Native ext_vector_type for the builtins.

typedef float vf4 __attribute__((ext_vector_type(4)));

__device__ __forceinline__ float quant1(float v) {
    // ceil(v - 0.5) == round-to-nearest with ties DOWN (exact in fp32 for |v|<2^23)
    float r = ceilf(v - 0.5f);
    r = fmaxf(-7.0f, fminf(8.0f, r));
    return r + 0.0f;  // normalize -0.0 -> +0.0
}

__device__ __forceinline__ vf4 quant4(vf4 v) {
    vf4 r;
    r.x = quant1(v.x);
    r.y = quant1(v.y);
    r.z = quant1(v.z);
    r.w = quant1(v.w);
    return r;
}

__global__ void __launch_bounds__(256) quant_kernel(const vf4* __restrict__ x,
                                                    vf4* __restrict__ out,
                                                    int n4) {
    // Block b covers vf4 indices [b*1024, b*1024+1024); thread t handles
    // t + {0,256,512,768} within that — fully coalesced per wave.
    int base = blockIdx.x * 1024 + threadIdx.x;
    int i0 = base;
    int i1 = base + 256;
    int i2 = base + 512;
    int i3 = base + 768;
    if (i3 < n4) {
        vf4 v0 = __builtin_nontemporal_load(&x[i0]);
        vf4 v1 = __builtin_nontemporal_load(&x[i1]);
        vf4 v2 = __builtin_nontemporal_load(&x[i2]);
        vf4 v3 = __builtin_nontemporal_load(&x[i3]);
        __builtin_nontemporal_store(quant4(v0), &out[i0]);
        __builtin_nontemporal_store(quant4(v1), &out[i1]);
        __builtin_nontemporal_store(quant4(v2), &out[i2]);
        __builtin_nontemporal_store(quant4(v3), &out[i3]);
    } else {
        if (i0 < n4) out[i0] = quant4(x[i0]);
        if (i1 < n4) out[i1] = quant4(x[i1]);
        if (i2 < n4) out[i2] = quant4(x[i2]);
    }
}

extern "C" void kernel_launch(void* const* d_in, const int* in_sizes, int n_in,
                              void* d_out, int out_size, void* d_ws, size_t ws_size,
                              hipStream_t stream) {
    const float* x = (const float*)d_in[0];
    float* out = (float*)d_out;
    int n = out_size;              // 16*64*64*64 = 4194304
    int n4 = n / 4;                // 1048576 vf4 elements
    int block = 256;
    int grid = (n4 + 1023) / 1024; // 1024 blocks, 4 vf4 per thread
    quant_kernel<<<grid, block, 0, stream>>>((const vf4*)x, (vf4*)out, n4);
}